// Round 7
// baseline (123.781 us; speedup 1.0000x reference)
//
#include <hip/hip_runtime.h>
#include <hip/hip_bf16.h>
#include <math.h>

#define B_ 4
#define L_ 2048
#define H_ 8
#define E_ 64
#define HE 512   // H_*E_ : float stride between consecutive seq positions

typedef short bf16x8 __attribute__((ext_vector_type(8)));
typedef float f32x4 __attribute__((ext_vector_type(4)));
typedef float f32x16 __attribute__((ext_vector_type(16)));
typedef unsigned short u16x4 __attribute__((ext_vector_type(4)));
typedef unsigned short u16x8 __attribute__((ext_vector_type(8)));

__device__ __forceinline__ unsigned short f2b(float f) {
  return __builtin_bit_cast(unsigned short, (__hip_bfloat16)f);
}
__device__ __forceinline__ unsigned cvtpk(float lo, float hi) {
  unsigned r;
  asm("v_cvt_pk_bf16_f32 %0, %1, %2" : "=v"(r) : "v"(lo), "v"(hi));
  return r;
}
__device__ __forceinline__ void pl32swap(unsigned &a, unsigned &b) {
  asm volatile("v_permlane32_swap_b32 %0, %1" : "+v"(a), "+v"(b));
}

// Flash attention fwd, causal, tau-scaled.
// Block = 8 waves, QBLK=128. INTRA-BLOCK KV-SPLIT: waves 0-3 process even
// 64-kv tiles, waves 4-7 odd tiles (same q rows) -> per-wave iterations
// halve, resident waves double (vs R5). Inner loop = R5's verified path:
// 32x32x16 MFMA, swapped QK^T (lane-local softmax), T12 cvt_pk+permlane,
// T13 defer-max, T14 early loads, double-buffered swizzled LDS.
// Final merge of the two online-softmax states via LDS (aliases K/V bufs).
__global__ __launch_bounds__(512, 4) void attn_fwd(
    const float* __restrict__ Q, const float* __restrict__ K,
    const float* __restrict__ V, const float* __restrict__ tau,
    float* __restrict__ O)
{
  // balanced remap: CU c gets flat {c, c+256} -> qt {j, 15-j} (17 tile-units
  // per pair); (b,h) fixed per flat%32 -> q-tiles of one (b,h) share an XCD.
  const int f  = blockIdx.x + 16 * (blockIdx.y + 8 * blockIdx.z);
  const int u  = f >> 5, hb = f & 31;
  const int h  = hb & 7, b = hb >> 3;
  const int qt = (u < 8) ? u : 23 - u;

  const int tid  = threadIdx.x;
  const int wave = tid >> 6, lane = tid & 63;
  const int l31 = lane & 31, hi = lane >> 5;
  const int l7 = l31 & 7;
  const int half = wave >> 2, wv = wave & 3;   // kv-half, q-subtile

  __shared__ union {
    struct { unsigned short Kt[2][2][64 * 64];   // [half][buf][kv][e]
             unsigned short Vt[2][2][64 * 64]; } kv;  // [half][buf][d][kv]
    struct { float O[128][64]; float m[128]; float l[128]; } cmb;
  } sm;

  const float qscale = 0.125f * expf(tau[b]) * 1.44269504088896f;
  const int q0w = qt * 128 + wv * 32;          // wave's first q-row
  const int myq = q0w + l31;                   // lane's q (dup over hi)
  const int dqd = 32 * wv + l31 - 64 * half;   // diagonal mask bound
  const bool skipw = (half == 1) && (wv < 2);  // fully-masked diagonal tile

  // Q fragments (B operand): qf[ks][j] = Q[myq][16ks + 8hi + j]
  const float* Qb = Q + (((size_t)b * L_ + myq) * H_ + h) * E_;
  bf16x8 qf[4];
  #pragma unroll
  for (int ks = 0; ks < 4; ++ks) {
    f32x4 a = *(const f32x4*)(Qb + ks * 16 + hi * 8);
    f32x4 c = *(const f32x4*)(Qb + ks * 16 + hi * 8 + 4);
    #pragma unroll
    for (int j = 0; j < 4; ++j) {
      qf[ks][j]     = (short)f2b(a[j] * qscale);
      qf[ks][4 + j] = (short)f2b(c[j] * qscale);
    }
  }

  float m_run = -INFINITY, l_run = 0.0f;       // stats of q = myq
  f32x16 oacc[2];
  #pragma unroll
  for (int nd = 0; nd < 2; ++nd)
    #pragma unroll
    for (int r = 0; r < 16; ++r) oacc[nd][r] = 0.0f;

  // ---- staging maps: threads <256 stage half 0, >=256 stage half 1 ----
  const int hs = tid >> 8, st = tid & 255;
  const int krow = st >> 2, kcg = st & 3;
  const int vkv = (st & 15) * 4, vd = (st >> 4) * 4;
  const size_t bh = ((size_t)b * L_ * H_ + h) * E_;
  const float* Kp = K + bh + (size_t)(64 * hs + krow) * HE + kcg * 16;
  const float* Vp = V + bh + (size_t)(64 * hs + vkv) * HE + vd;
  const int kwo0 = krow * 64 + (((2 * kcg)     ^ (krow & 7)) << 3);
  const int kwo1 = krow * 64 + (((2 * kcg + 1) ^ (krow & 7)) << 3);

  const int nt = qt + 1;   // iterations; half h_ sees tiles 2i + h_

  f32x4 kq[4], vq[4];
  // ---- prologue: load + stage tile (2*0 + hs) into buf 0 ----
  #pragma unroll
  for (int i = 0; i < 4; ++i) kq[i] = *(const f32x4*)(Kp + 4 * i);
  #pragma unroll
  for (int i = 0; i < 4; ++i) vq[i] = *(const f32x4*)(Vp + (size_t)i * HE);
  {
    u16x8 w0, w1;
    #pragma unroll
    for (int j = 0; j < 4; ++j) {
      w0[j] = f2b(kq[0][j]); w0[4 + j] = f2b(kq[1][j]);
      w1[j] = f2b(kq[2][j]); w1[4 + j] = f2b(kq[3][j]);
    }
    *(u16x8*)(&sm.kv.Kt[hs][0][kwo0]) = w0;
    *(u16x8*)(&sm.kv.Kt[hs][0][kwo1]) = w1;
    #pragma unroll
    for (int jd = 0; jd < 4; ++jd) {
      const int row = vd + jd;
      u16x4 vw;
      #pragma unroll
      for (int i = 0; i < 4; ++i) vw[i] = f2b(vq[i][jd]);
      *(u16x4*)(&sm.kv.Vt[hs][0][row * 64 + (((vkv >> 3) ^ (row & 7)) << 3) + (vkv & 7)]) = vw;
    }
  }
  __syncthreads();
  int cur = 0;

  for (int t = 0; t < nt; ++t) {
    const bool havenext = (t + 1 < nt);
    if (havenext) {   // T14: issue next-tile loads early, LDS-write late
      const float* Kn = Kp + (size_t)(t + 1) * 128 * HE;
      const float* Vn = Vp + (size_t)(t + 1) * 128 * HE;
      #pragma unroll
      for (int i = 0; i < 4; ++i) kq[i] = *(const f32x4*)(Kn + 4 * i);
      #pragma unroll
      for (int i = 0; i < 4; ++i) vq[i] = *(const f32x4*)(Vn + (size_t)i * HE);
    }

    if (!(skipw && t == nt - 1)) {
      const unsigned short* Kl = sm.kv.Kt[half][cur];
      const unsigned short* Vl = sm.kv.Vt[half][cur];

      // ---- S^T = K Q^T : 8 MFMAs ----
      f32x16 sacc[2];
      #pragma unroll
      for (int mt = 0; mt < 2; ++mt)
        #pragma unroll
        for (int r = 0; r < 16; ++r) sacc[mt][r] = 0.0f;
      __builtin_amdgcn_s_setprio(1);
      #pragma unroll
      for (int ks = 0; ks < 4; ++ks) {
        #pragma unroll
        for (int mt = 0; mt < 2; ++mt) {
          bf16x8 kf = *(const bf16x8*)(Kl + (32 * mt + l31) * 64 +
                                       (((2 * ks + hi) ^ l7) << 3));
          sacc[mt] = __builtin_amdgcn_mfma_f32_32x32x16_bf16(kf, qf[ks], sacc[mt], 0, 0, 0);
        }
      }
      __builtin_amdgcn_s_setprio(0);

      // ---- causal mask (diagonal iteration only) ----
      if (t == nt - 1) {
        #pragma unroll
        for (int mt = 0; mt < 2; ++mt)
          #pragma unroll
          for (int r = 0; r < 16; ++r) {
            const int kvl = 32 * mt + (r & 3) + 8 * (r >> 2) + 4 * hi;
            if (kvl > dqd) sacc[mt][r] = -3.0e38f;
          }
      }

      // ---- online softmax: balanced max tree + defer-max (T13) ----
      float p0 = sacc[0][0], p1 = sacc[0][1], p2 = sacc[0][2], p3 = sacc[0][3];
      #pragma unroll
      for (int mt = 0; mt < 2; ++mt)
        #pragma unroll
        for (int r = (mt == 0 ? 4 : 0); r < 16; r += 4) {
          p0 = fmaxf(p0, sacc[mt][r]);
          p1 = fmaxf(p1, sacc[mt][r + 1]);
          p2 = fmaxf(p2, sacc[mt][r + 2]);
          p3 = fmaxf(p3, sacc[mt][r + 3]);
        }
      float mx = fmaxf(fmaxf(p0, p1), fmaxf(p2, p3));
      mx = fmaxf(mx, __shfl_xor(mx, 32));

      if (!__all(mx - m_run <= 8.0f)) {      // rescale needed (rare)
        const float mnew = fmaxf(m_run, mx);
        const float corr = exp2f(m_run - mnew);   // first tile: exp2(-inf)=0
        m_run = mnew;
        l_run *= corr;
        #pragma unroll
        for (int r = 0; r < 16; ++r) {
          const int qrow = (r & 3) + 8 * (r >> 2) + 4 * hi;
          const float cr = __shfl(corr, qrow);
          oacc[0][r] *= cr;
          oacc[1][r] *= cr;
        }
      }

      float s0 = 0.f, s1 = 0.f, s2 = 0.f, s3 = 0.f;
      #pragma unroll
      for (int mt = 0; mt < 2; ++mt)
        #pragma unroll
        for (int r = 0; r < 16; r += 4) {
          float e0 = exp2f(sacc[mt][r]     - m_run);
          float e1 = exp2f(sacc[mt][r + 1] - m_run);
          float e2 = exp2f(sacc[mt][r + 2] - m_run);
          float e3 = exp2f(sacc[mt][r + 3] - m_run);
          sacc[mt][r] = e0; sacc[mt][r + 1] = e1;
          sacc[mt][r + 2] = e2; sacc[mt][r + 3] = e3;
          s0 += e0; s1 += e1; s2 += e2; s3 += e3;
        }
      float rs = (s0 + s1) + (s2 + s3);
      rs += __shfl_xor(rs, 32);
      l_run += rs;

      // ---- P -> bf16 packed words (T12 step 1) ----
      unsigned pk[2][8];
      #pragma unroll
      for (int mt = 0; mt < 2; ++mt)
        #pragma unroll
        for (int i = 0; i < 8; ++i)
          pk[mt][i] = cvtpk(sacc[mt][2 * i], sacc[mt][2 * i + 1]);

      // ---- O += P V : 8 MFMAs; pf via permlane32_swap (T12 step 2) ----
      __builtin_amdgcn_s_setprio(1);
      #pragma unroll
      for (int ks = 0; ks < 4; ++ks) {
        const int c = ks & 1, mtx = ks >> 1;
        unsigned a  = pk[mtx][4 * c];
        unsigned y  = pk[mtx][4 * c + 2];
        unsigned a2 = pk[mtx][4 * c + 1];
        unsigned y2 = pk[mtx][4 * c + 3];
        pl32swap(a, y);
        pl32swap(a2, y2);
        union { unsigned w[4]; bf16x8 v; } pu;
        pu.w[0] = a; pu.w[1] = a2; pu.w[2] = y; pu.w[3] = y2;
        #pragma unroll
        for (int nd = 0; nd < 2; ++nd) {
          bf16x8 vf = *(const bf16x8*)(Vl + (32 * nd + l31) * 64 +
                                       (((2 * ks + hi) ^ l7) << 3));
          oacc[nd] = __builtin_amdgcn_mfma_f32_32x32x16_bf16(pu.v, vf, oacc[nd], 0, 0, 0);
        }
      }
      __builtin_amdgcn_s_setprio(0);
    }

    if (havenext) {
      const int nb = cur ^ 1;
      u16x8 w0, w1;
      #pragma unroll
      for (int j = 0; j < 4; ++j) {
        w0[j] = f2b(kq[0][j]); w0[4 + j] = f2b(kq[1][j]);
        w1[j] = f2b(kq[2][j]); w1[4 + j] = f2b(kq[3][j]);
      }
      *(u16x8*)(&sm.kv.Kt[hs][nb][kwo0]) = w0;
      *(u16x8*)(&sm.kv.Kt[hs][nb][kwo1]) = w1;
      #pragma unroll
      for (int jd = 0; jd < 4; ++jd) {
        const int row = vd + jd;
        u16x4 vw;
        #pragma unroll
        for (int i = 0; i < 4; ++i) vw[i] = f2b(vq[i][jd]);
        *(u16x4*)(&sm.kv.Vt[hs][nb][row * 64 + (((vkv >> 3) ^ (row & 7)) << 3) + (vkv & 7)]) = vw;
      }
      __syncthreads();
      cur = nb;
    }
  }

  // ---- merge the two kv-halves (LDS aliases K/V buffers; barriered) ----
  __syncthreads();                  // all compute LDS reads done
  if (half == 1) {                  // publish unnormalized state
    #pragma unroll
    for (int r = 0; r < 16; ++r) {
      const int qrow = (r & 3) + 8 * (r >> 2) + 4 * hi;
      sm.cmb.O[32 * wv + qrow][l31]      = oacc[0][r];
      sm.cmb.O[32 * wv + qrow][32 + l31] = oacc[1][r];
    }
    if (hi == 0) { sm.cmb.m[32 * wv + l31] = m_run; sm.cmb.l[32 * wv + l31] = l_run; }
  }
  __syncthreads();
  if (half == 0) {                  // merge + normalize + store
    const float m_b = sm.cmb.m[32 * wv + l31];
    const float l_b = sm.cmb.l[32 * wv + l31];
    const float mm = fmaxf(m_run, m_b);
    const float sa = exp2f(m_run - mm);
    const float sb = exp2f(m_b - mm);          // m_b=-inf (empty half) -> 0
    const float linv = 1.0f / (sa * l_run + sb * l_b);
    const float wa = sa * linv, wb = sb * linv;
    float* Ob = O + (((size_t)b * L_ + q0w) * H_ + h) * E_;
    #pragma unroll
    for (int r = 0; r < 16; ++r) {
      const int qrow = (r & 3) + 8 * (r >> 2) + 4 * hi;
      const float wa_r = __shfl(wa, qrow);
      const float wb_r = __shfl(wb, qrow);
      Ob[(size_t)qrow * HE + l31] =
          wa_r * oacc[0][r] + wb_r * sm.cmb.O[32 * wv + qrow][l31];
      Ob[(size_t)qrow * HE + 32 + l31] =
          wa_r * oacc[1][r] + wb_r * sm.cmb.O[32 * wv + qrow][32 + l31];
    }
  }
}

extern "C" void kernel_launch(void* const* d_in, const int* in_sizes, int n_in,
                              void* d_out, int out_size, void* d_ws, size_t ws_size,
                              hipStream_t stream) {
  (void)in_sizes; (void)n_in; (void)out_size; (void)d_ws; (void)ws_size;
  const float* Q   = (const float*)d_in[0];
  const float* K   = (const float*)d_in[1];
  const float* V   = (const float*)d_in[2];
  // d_in[3] = attn_mask: ignored, causality applied analytically.
  const float* tau = (const float*)d_in[4];
  float* O = (float*)d_out;
  dim3 grid(L_ / 128, H_, B_), block(512);
  hipLaunchKernelGGL(attn_fwd, grid, block, 0, stream, Q, K, V, tau, O);
}

// Round 8
// 61.325 us; speedup vs baseline: 2.0184x; 2.0184x over previous
//
#include <hip/hip_runtime.h>
#include <hip/hip_bf16.h>
#include <math.h>

#define B_ 4
#define L_ 2048
#define H_ 8
#define E_ 64
#define HE 512   // H_*E_ : float stride between consecutive seq positions

typedef short bf16x8 __attribute__((ext_vector_type(8)));
typedef float f32x4 __attribute__((ext_vector_type(4)));
typedef float f32x16 __attribute__((ext_vector_type(16)));
typedef unsigned short u16x4 __attribute__((ext_vector_type(4)));
typedef unsigned short u16x8 __attribute__((ext_vector_type(8)));

__device__ __forceinline__ unsigned short f2b(float f) {
  return __builtin_bit_cast(unsigned short, (__hip_bfloat16)f);
}
__device__ __forceinline__ unsigned cvtpk(float lo, float hi) {
  unsigned r;
  asm("v_cvt_pk_bf16_f32 %0, %1, %2" : "=v"(r) : "v"(lo), "v"(hi));
  return r;
}
__device__ __forceinline__ void pl32swap(unsigned &a, unsigned &b) {
  asm volatile("v_permlane32_swap_b32 %0, %1" : "+v"(a), "+v"(b));
}

// Flash attention fwd, causal, tau-scaled.
// Block = 4 waves, 32 q-rows/wave (QBLK=128), KV tile 64.
// SOFTWARE-PIPELINED across tiles: iteration t issues QK(t+1) MFMAs first,
// then softmax(t) on registers produced last iteration (VALU overlaps the
// matrix pipe), then PV(t). 3-buffer LDS rotation -> one barrier/iter, no
// WAR race. 32x32x16 MFMA, swapped QK^T (lane-local softmax), T12
// cvt_pk+permlane32_swap, T13 defer-max, T14 early loads.
__global__ __launch_bounds__(256, 2) void attn_fwd(
    const float* __restrict__ Q, const float* __restrict__ K,
    const float* __restrict__ V, const float* __restrict__ tau,
    float* __restrict__ O)
{
  // balanced remap: CU c gets flat {c, c+256} -> qt {j, 15-j}; (b,h) per
  // flat%32 -> all q-tiles of one (b,h) on one XCD.
  const int f  = blockIdx.x + 16 * (blockIdx.y + 8 * blockIdx.z);
  const int u  = f >> 5, hb = f & 31;
  const int h  = hb & 7, b = hb >> 3;
  const int qt = (u < 8) ? u : 23 - u;

  const int tid  = threadIdx.x;
  const int wave = tid >> 6, lane = tid & 63;
  const int l31 = lane & 31, hi = lane >> 5;
  const int l7 = l31 & 7;

  __shared__ unsigned short ldsK[3][64 * 64];  // [buf][kv][e], swizzled
  __shared__ unsigned short ldsV[3][64 * 64];  // [buf][d][kv], swizzled

  const float qscale = 0.125f * expf(tau[b]) * 1.44269504088896f;
  const int q0w = qt * 128 + wave * 32;        // wave's first q-row
  const int myq = q0w + l31;                   // lane's q (dup over hi)

  // Q fragments (B operand): qf[ks][j] = Q[myq][16ks + 8hi + j]
  const float* Qb = Q + (((size_t)b * L_ + myq) * H_ + h) * E_;
  bf16x8 qf[4];
  #pragma unroll
  for (int ks = 0; ks < 4; ++ks) {
    f32x4 a = *(const f32x4*)(Qb + ks * 16 + hi * 8);
    f32x4 c = *(const f32x4*)(Qb + ks * 16 + hi * 8 + 4);
    #pragma unroll
    for (int j = 0; j < 4; ++j) {
      qf[ks][j]     = (short)f2b(a[j] * qscale);
      qf[ks][4 + j] = (short)f2b(c[j] * qscale);
    }
  }

  float m_run = -INFINITY, l_run = 0.0f;       // stats of q = myq
  f32x16 oacc[2];
  #pragma unroll
  for (int nd = 0; nd < 2; ++nd)
    #pragma unroll
    for (int r = 0; r < 16; ++r) oacc[nd][r] = 0.0f;

  // staging maps: K: row=tid>>2, 16-float chunk (tid&3); V: 4x4 transpose
  const int krow = tid >> 2, kcg = tid & 3;
  const int vkv = (tid & 15) * 4, vd = (tid >> 4) * 4;
  const size_t bh = ((size_t)b * L_ * H_ + h) * E_;
  const float* Kp = K + bh + (size_t)krow * HE + kcg * 16;
  const float* Vp = V + bh + (size_t)vkv * HE + vd;
  const int kwo0 = krow * 64 + (((2 * kcg)     ^ (krow & 7)) << 3);
  const int kwo1 = krow * 64 + (((2 * kcg + 1) ^ (krow & 7)) << 3);

  const int nt = 2 * qt + 2;                   // even; 64-kv tiles
  const int tmaxw = 2 * qt + (wave >> 1);      // wave's diagonal tile

  auto load_tile = [&](int t, f32x4 (&kq)[4], f32x4 (&vq)[4]) {
    const float* Kn = Kp + (size_t)t * 64 * HE;
    const float* Vn = Vp + (size_t)t * 64 * HE;
    #pragma unroll
    for (int i = 0; i < 4; ++i) kq[i] = *(const f32x4*)(Kn + 4 * i);
    #pragma unroll
    for (int i = 0; i < 4; ++i) vq[i] = *(const f32x4*)(Vn + (size_t)i * HE);
  };
  auto stage_write = [&](int nb, const f32x4 (&kq)[4], const f32x4 (&vq)[4]) {
    u16x8 w0, w1;
    #pragma unroll
    for (int j = 0; j < 4; ++j) {
      w0[j] = f2b(kq[0][j]); w0[4 + j] = f2b(kq[1][j]);
      w1[j] = f2b(kq[2][j]); w1[4 + j] = f2b(kq[3][j]);
    }
    *(u16x8*)(&ldsK[nb][kwo0]) = w0;
    *(u16x8*)(&ldsK[nb][kwo1]) = w1;
    #pragma unroll
    for (int jd = 0; jd < 4; ++jd) {
      const int row = vd + jd;
      u16x4 vw;
      #pragma unroll
      for (int i = 0; i < 4; ++i) vw[i] = f2b(vq[i][jd]);
      *(u16x4*)(&ldsV[nb][row * 64 + (((vkv >> 3) ^ (row & 7)) << 3) + (vkv & 7)]) = vw;
    }
  };
  auto qk = [&](int bn, f32x16 (&s)[2]) {      // S^T = K Q^T, 8 MFMAs
    const unsigned short* Kl = ldsK[bn];
    #pragma unroll
    for (int mt = 0; mt < 2; ++mt)
      #pragma unroll
      for (int r = 0; r < 16; ++r) s[mt][r] = 0.0f;
    __builtin_amdgcn_s_setprio(1);
    #pragma unroll
    for (int ks = 0; ks < 4; ++ks) {
      #pragma unroll
      for (int mt = 0; mt < 2; ++mt) {
        bf16x8 kf = *(const bf16x8*)(Kl + (32 * mt + l31) * 64 +
                                     (((2 * ks + hi) ^ l7) << 3));
        s[mt] = __builtin_amdgcn_mfma_f32_32x32x16_bf16(kf, qf[ks], s[mt], 0, 0, 0);
      }
    }
    __builtin_amdgcn_s_setprio(0);
  };
  auto soft_pv = [&](int t, int bc, f32x16 (&s)[2]) {
    // causal mask (diagonal tile only)
    if (t == tmaxw) {
      const int dq = myq - 64 * t;             // keep kv_local <= dq
      #pragma unroll
      for (int mt = 0; mt < 2; ++mt)
        #pragma unroll
        for (int r = 0; r < 16; ++r) {
          const int kvl = 32 * mt + (r & 3) + 8 * (r >> 2) + 4 * hi;
          if (kvl > dq) s[mt][r] = -3.0e38f;
        }
    }
    // online softmax: balanced max tree + defer-max (T13)
    float p0 = s[0][0], p1 = s[0][1], p2 = s[0][2], p3 = s[0][3];
    #pragma unroll
    for (int mt = 0; mt < 2; ++mt)
      #pragma unroll
      for (int r = (mt == 0 ? 4 : 0); r < 16; r += 4) {
        p0 = fmaxf(p0, s[mt][r]);
        p1 = fmaxf(p1, s[mt][r + 1]);
        p2 = fmaxf(p2, s[mt][r + 2]);
        p3 = fmaxf(p3, s[mt][r + 3]);
      }
    float mx = fmaxf(fmaxf(p0, p1), fmaxf(p2, p3));
    mx = fmaxf(mx, __shfl_xor(mx, 32));
    if (!__all(mx - m_run <= 8.0f)) {          // rescale (rare)
      const float mnew = fmaxf(m_run, mx);
      const float corr = exp2f(m_run - mnew);  // first tile: exp2(-inf)=0
      m_run = mnew;
      l_run *= corr;
      #pragma unroll
      for (int r = 0; r < 16; ++r) {
        const int qrow = (r & 3) + 8 * (r >> 2) + 4 * hi;
        const float cr = __shfl(corr, qrow);
        oacc[0][r] *= cr;
        oacc[1][r] *= cr;
      }
    }
    float s0 = 0.f, s1 = 0.f, s2 = 0.f, s3 = 0.f;
    #pragma unroll
    for (int mt = 0; mt < 2; ++mt)
      #pragma unroll
      for (int r = 0; r < 16; r += 4) {
        float e0 = exp2f(s[mt][r]     - m_run);
        float e1 = exp2f(s[mt][r + 1] - m_run);
        float e2 = exp2f(s[mt][r + 2] - m_run);
        float e3 = exp2f(s[mt][r + 3] - m_run);
        s[mt][r] = e0; s[mt][r + 1] = e1;
        s[mt][r + 2] = e2; s[mt][r + 3] = e3;
        s0 += e0; s1 += e1; s2 += e2; s3 += e3;
      }
    float rs = (s0 + s1) + (s2 + s3);
    rs += __shfl_xor(rs, 32);
    l_run += rs;
    // P -> bf16 packed (T12 step 1)
    unsigned pk[2][8];
    #pragma unroll
    for (int mt = 0; mt < 2; ++mt)
      #pragma unroll
      for (int i = 0; i < 8; ++i)
        pk[mt][i] = cvtpk(s[mt][2 * i], s[mt][2 * i + 1]);
    // O += P V : 8 MFMAs; pf via permlane32_swap (T12 step 2)
    const unsigned short* Vl = ldsV[bc];
    __builtin_amdgcn_s_setprio(1);
    #pragma unroll
    for (int ks = 0; ks < 4; ++ks) {
      const int c = ks & 1, mtx = ks >> 1;
      unsigned a  = pk[mtx][4 * c];
      unsigned y  = pk[mtx][4 * c + 2];
      unsigned a2 = pk[mtx][4 * c + 1];
      unsigned y2 = pk[mtx][4 * c + 3];
      pl32swap(a, y);
      pl32swap(a2, y2);
      union { unsigned w[4]; bf16x8 v; } pu;
      pu.w[0] = a; pu.w[1] = a2; pu.w[2] = y; pu.w[3] = y2;
      #pragma unroll
      for (int nd = 0; nd < 2; ++nd) {
        bf16x8 vf = *(const bf16x8*)(Vl + (32 * nd + l31) * 64 +
                                     (((2 * ks + hi) ^ l7) << 3));
        oacc[nd] = __builtin_amdgcn_mfma_f32_32x32x16_bf16(pu.v, vf, oacc[nd], 0, 0, 0);
      }
    }
    __builtin_amdgcn_s_setprio(0);
  };

  // ---- prologue: stage tiles 0,1; QK(0) ----
  f32x16 sA[2], sB[2];
  {
    f32x4 k0[4], v0[4], k1[4], v1[4];
    load_tile(0, k0, v0);
    load_tile(1, k1, v1);
    stage_write(0, k0, v0);
    __syncthreads();
    qk(0, sA);
    stage_write(1, k1, v1);
    __syncthreads();
  }

  // ---- main loop, 2x unrolled (sacc role swap; nt is even) ----
  auto body = [&](int t, f32x16 (&scur)[2], f32x16 (&snxt)[2]) {
    const int bc = t % 3, bn = (t + 1) % 3, bs = (t + 2) % 3;
    f32x4 kq[4], vq[4];
    const bool stage = (t + 2 < nt);
    if (stage) load_tile(t + 2, kq, vq);       // T14: issue early
    if ((t + 1 < nt) && (t + 1 <= tmaxw)) qk(bn, snxt);  // overlaps softmax
    if (t <= tmaxw) soft_pv(t, bc, scur);
    if (stage) stage_write(bs, kq, vq);
    __syncthreads();
  };
  for (int t = 0; t < nt; t += 2) {
    body(t, sA, sB);
    body(t + 1, sB, sA);
  }

  // ---- epilogue: normalize and store f32 ----
  const float linv = 1.0f / l_run;
  float* Ob = O + (((size_t)b * L_ + q0w) * H_ + h) * E_;
  #pragma unroll
  for (int r = 0; r < 16; ++r) {
    const int qrow = (r & 3) + 8 * (r >> 2) + 4 * hi;
    const float inv = __shfl(linv, qrow);
    Ob[(size_t)qrow * HE + l31]      = oacc[0][r] * inv;
    Ob[(size_t)qrow * HE + 32 + l31] = oacc[1][r] * inv;
  }
}

extern "C" void kernel_launch(void* const* d_in, const int* in_sizes, int n_in,
                              void* d_out, int out_size, void* d_ws, size_t ws_size,
                              hipStream_t stream) {
  (void)in_sizes; (void)n_in; (void)out_size; (void)d_ws; (void)ws_size;
  const float* Q   = (const float*)d_in[0];
  const float* K   = (const float*)d_in[1];
  const float* V   = (const float*)d_in[2];
  // d_in[3] = attn_mask: ignored, causality applied analytically.
  const float* tau = (const float*)d_in[4];
  float* O = (float*)d_out;
  dim3 grid(L_ / 128, H_, B_), block(256);
  hipLaunchKernelGGL(attn_fwd, grid, block, 0, stream, Q, K, V, tau, O);
}

// Round 10
// 53.310 us; speedup vs baseline: 2.3219x; 1.1504x over previous
//
#include <hip/hip_runtime.h>
#include <hip/hip_bf16.h>
#include <math.h>

#define B_ 4
#define L_ 2048
#define H_ 8
#define E_ 64
#define HE 512   // H_*E_ : float stride between consecutive seq positions

typedef short bf16x8 __attribute__((ext_vector_type(8)));
typedef float f32x4 __attribute__((ext_vector_type(4)));
typedef float f32x16 __attribute__((ext_vector_type(16)));
typedef unsigned short u16x4 __attribute__((ext_vector_type(4)));
typedef unsigned short u16x8 __attribute__((ext_vector_type(8)));

__device__ __forceinline__ unsigned short f2b(float f) {
  return __builtin_bit_cast(unsigned short, (__hip_bfloat16)f);
}
__device__ __forceinline__ unsigned cvtpk(float lo, float hi) {
  unsigned r;
  asm("v_cvt_pk_bf16_f32 %0, %1, %2" : "=v"(r) : "v"(lo), "v"(hi));
  return r;
}
// NOTE: operands MUST be distinct values; if both inputs hold the same
// value the allocator may coalesce them into one VGPR (R9 failure).
__device__ __forceinline__ void pl32swap(unsigned &a, unsigned &b) {
  asm volatile("v_permlane32_swap_b32 %0, %1" : "+v"(a), "+v"(b));
}

// Flash attention fwd, causal, tau-scaled.
// Block = 8 waves, QBLK=128. INTRA-BLOCK KV-SPLIT: waves 0-3 process even
// 64-kv tiles, waves 4-7 odd tiles (same q rows) -> per-wave iterations
// halve, 8 waves resident. Inner loop: 32x32x16 MFMA, swapped QK^T
// (lane-local softmax), T12 cvt_pk+permlane, T13 defer-max, T14 early
// loads, double-buffered swizzled LDS. Final merge of the two softmax
// states via LDS (aliases K/V bufs). launch_bounds(512,1): no VGPR cap
// (R7's spill was launch_bounds(512,4) -> 64-VGPR cap -> scratch traffic).
__global__ __launch_bounds__(512, 1) void attn_fwd(
    const float* __restrict__ Q, const float* __restrict__ K,
    const float* __restrict__ V, const float* __restrict__ tau,
    float* __restrict__ O)
{
  // balanced remap: CU c gets flat {c, c+256} -> qt {j, 15-j} (17 tile-units
  // per pair); (b,h) fixed per flat%32 -> q-tiles of one (b,h) share an XCD.
  const int f  = blockIdx.x + 16 * (blockIdx.y + 8 * blockIdx.z);
  const int u  = f >> 5, hb = f & 31;
  const int h  = hb & 7, b = hb >> 3;
  const int qt = (u < 8) ? u : 23 - u;

  const int tid  = threadIdx.x;
  const int wave = tid >> 6, lane = tid & 63;
  const int l31 = lane & 31, hi = lane >> 5;
  const int l7 = l31 & 7;
  const int half = wave >> 2, wv = wave & 3;   // kv-half, q-subtile

  __shared__ union {
    struct { unsigned short Kt[2][2][64 * 64];   // [half][buf][kv][e]
             unsigned short Vt[2][2][64 * 64]; } kv;  // [half][buf][d][kv]
    struct { float O[128][64]; float m[128]; float l[128]; } cmb;
  } sm;

  const float qscale = 0.125f * expf(tau[b]) * 1.44269504088896f;
  const int q0w = qt * 128 + wv * 32;          // wave's first q-row
  const int myq = q0w + l31;                   // lane's q (dup over hi)
  const int dqd = 32 * wv + l31 - 64 * half;   // diagonal mask bound
  const bool skipw = (half == 1) && (wv < 2);  // fully-masked diagonal tile

  // Q fragments (B operand): qf[ks][j] = Q[myq][16ks + 8hi + j]
  const float* Qb = Q + (((size_t)b * L_ + myq) * H_ + h) * E_;
  bf16x8 qf[4];
  #pragma unroll
  for (int ks = 0; ks < 4; ++ks) {
    f32x4 a = *(const f32x4*)(Qb + ks * 16 + hi * 8);
    f32x4 c = *(const f32x4*)(Qb + ks * 16 + hi * 8 + 4);
    #pragma unroll
    for (int j = 0; j < 4; ++j) {
      qf[ks][j]     = (short)f2b(a[j] * qscale);
      qf[ks][4 + j] = (short)f2b(c[j] * qscale);
    }
  }

  float m_run = -INFINITY, l_run = 0.0f;       // stats of q = myq
  f32x16 oacc[2];
  #pragma unroll
  for (int nd = 0; nd < 2; ++nd)
    #pragma unroll
    for (int r = 0; r < 16; ++r) oacc[nd][r] = 0.0f;

  // ---- staging maps: threads <256 stage half 0, >=256 stage half 1 ----
  const int hs = tid >> 8, st = tid & 255;
  const int krow = st >> 2, kcg = st & 3;
  const int vkv = (st & 15) * 4, vd = (st >> 4) * 4;
  const size_t bh = ((size_t)b * L_ * H_ + h) * E_;
  const float* Kp = K + bh + (size_t)(64 * hs + krow) * HE + kcg * 16;
  const float* Vp = V + bh + (size_t)(64 * hs + vkv) * HE + vd;
  const int kwo0 = krow * 64 + (((2 * kcg)     ^ (krow & 7)) << 3);
  const int kwo1 = krow * 64 + (((2 * kcg + 1) ^ (krow & 7)) << 3);

  const int nt = qt + 1;   // iterations; half h_ sees tiles 2i + h_

  f32x4 kq[4], vq[4];
  // ---- prologue: load + stage tile (2*0 + hs) into buf 0 ----
  #pragma unroll
  for (int i = 0; i < 4; ++i) kq[i] = *(const f32x4*)(Kp + 4 * i);
  #pragma unroll
  for (int i = 0; i < 4; ++i) vq[i] = *(const f32x4*)(Vp + (size_t)i * HE);
  {
    u16x8 w0, w1;
    #pragma unroll
    for (int j = 0; j < 4; ++j) {
      w0[j] = f2b(kq[0][j]); w0[4 + j] = f2b(kq[1][j]);
      w1[j] = f2b(kq[2][j]); w1[4 + j] = f2b(kq[3][j]);
    }
    *(u16x8*)(&sm.kv.Kt[hs][0][kwo0]) = w0;
    *(u16x8*)(&sm.kv.Kt[hs][0][kwo1]) = w1;
    #pragma unroll
    for (int jd = 0; jd < 4; ++jd) {
      const int row = vd + jd;
      u16x4 vw;
      #pragma unroll
      for (int i = 0; i < 4; ++i) vw[i] = f2b(vq[i][jd]);
      *(u16x4*)(&sm.kv.Vt[hs][0][row * 64 + (((vkv >> 3) ^ (row & 7)) << 3) + (vkv & 7)]) = vw;
    }
  }
  __syncthreads();
  int cur = 0;

  for (int t = 0; t < nt; ++t) {
    const bool havenext = (t + 1 < nt);
    if (havenext) {   // T14: issue next-tile loads early, LDS-write late
      const float* Kn = Kp + (size_t)(t + 1) * 128 * HE;
      const float* Vn = Vp + (size_t)(t + 1) * 128 * HE;
      #pragma unroll
      for (int i = 0; i < 4; ++i) kq[i] = *(const f32x4*)(Kn + 4 * i);
      #pragma unroll
      for (int i = 0; i < 4; ++i) vq[i] = *(const f32x4*)(Vn + (size_t)i * HE);
    }

    if (!(skipw && t == nt - 1)) {
      const unsigned short* Kl = sm.kv.Kt[half][cur];
      const unsigned short* Vl = sm.kv.Vt[half][cur];

      // ---- S^T = K Q^T : 8 MFMAs ----
      f32x16 sacc[2];
      #pragma unroll
      for (int mt = 0; mt < 2; ++mt)
        #pragma unroll
        for (int r = 0; r < 16; ++r) sacc[mt][r] = 0.0f;
      __builtin_amdgcn_s_setprio(1);
      #pragma unroll
      for (int ks = 0; ks < 4; ++ks) {
        #pragma unroll
        for (int mt = 0; mt < 2; ++mt) {
          bf16x8 kf = *(const bf16x8*)(Kl + (32 * mt + l31) * 64 +
                                       (((2 * ks + hi) ^ l7) << 3));
          sacc[mt] = __builtin_amdgcn_mfma_f32_32x32x16_bf16(kf, qf[ks], sacc[mt], 0, 0, 0);
        }
      }
      __builtin_amdgcn_s_setprio(0);

      // ---- causal mask (diagonal iteration only) ----
      if (t == nt - 1) {
        #pragma unroll
        for (int mt = 0; mt < 2; ++mt)
          #pragma unroll
          for (int r = 0; r < 16; ++r) {
            const int kvl = 32 * mt + (r & 3) + 8 * (r >> 2) + 4 * hi;
            if (kvl > dqd) sacc[mt][r] = -3.0e38f;
          }
      }

      // ---- online softmax: balanced max tree + defer-max (T13) ----
      float p0 = sacc[0][0], p1 = sacc[0][1], p2 = sacc[0][2], p3 = sacc[0][3];
      #pragma unroll
      for (int mt = 0; mt < 2; ++mt)
        #pragma unroll
        for (int r = (mt == 0 ? 4 : 0); r < 16; r += 4) {
          p0 = fmaxf(p0, sacc[mt][r]);
          p1 = fmaxf(p1, sacc[mt][r + 1]);
          p2 = fmaxf(p2, sacc[mt][r + 2]);
          p3 = fmaxf(p3, sacc[mt][r + 3]);
        }
      float mx = fmaxf(fmaxf(p0, p1), fmaxf(p2, p3));
      mx = fmaxf(mx, __shfl_xor(mx, 32));      // proven cross-half reduce

      if (!__all(mx - m_run <= 8.0f)) {        // rescale needed (rare)
        const float mnew = fmaxf(m_run, mx);
        const float corr = exp2f(m_run - mnew);   // first tile: exp2(-inf)=0
        m_run = mnew;
        l_run *= corr;
        #pragma unroll
        for (int r = 0; r < 16; ++r) {
          const int qrow = (r & 3) + 8 * (r >> 2) + 4 * hi;
          const float cr = __shfl(corr, qrow);
          oacc[0][r] *= cr;
          oacc[1][r] *= cr;
        }
      }

      float s0 = 0.f, s1 = 0.f, s2 = 0.f, s3 = 0.f;
      #pragma unroll
      for (int mt = 0; mt < 2; ++mt)
        #pragma unroll
        for (int r = 0; r < 16; r += 4) {
          float e0 = exp2f(sacc[mt][r]     - m_run);
          float e1 = exp2f(sacc[mt][r + 1] - m_run);
          float e2 = exp2f(sacc[mt][r + 2] - m_run);
          float e3 = exp2f(sacc[mt][r + 3] - m_run);
          sacc[mt][r] = e0; sacc[mt][r + 1] = e1;
          sacc[mt][r + 2] = e2; sacc[mt][r + 3] = e3;
          s0 += e0; s1 += e1; s2 += e2; s3 += e3;
        }
      float rs = (s0 + s1) + (s2 + s3);
      rs += __shfl_xor(rs, 32);                // proven cross-half reduce
      l_run += rs;

      // ---- P -> bf16 packed words (T12 step 1) ----
      unsigned pk[2][8];
      #pragma unroll
      for (int mt = 0; mt < 2; ++mt)
        #pragma unroll
        for (int i = 0; i < 8; ++i)
          pk[mt][i] = cvtpk(sacc[mt][2 * i], sacc[mt][2 * i + 1]);

      // ---- O += P V : 8 MFMAs; pf via permlane32_swap (T12 step 2) ----
      __builtin_amdgcn_s_setprio(1);
      #pragma unroll
      for (int ks = 0; ks < 4; ++ks) {
        const int c = ks & 1, mtx = ks >> 1;
        unsigned a  = pk[mtx][4 * c];
        unsigned y  = pk[mtx][4 * c + 2];
        unsigned a2 = pk[mtx][4 * c + 1];
        unsigned y2 = pk[mtx][4 * c + 3];
        pl32swap(a, y);
        pl32swap(a2, y2);
        union { unsigned w[4]; bf16x8 v; } pu;
        pu.w[0] = a; pu.w[1] = a2; pu.w[2] = y; pu.w[3] = y2;
        #pragma unroll
        for (int nd = 0; nd < 2; ++nd) {
          bf16x8 vf = *(const bf16x8*)(Vl + (32 * nd + l31) * 64 +
                                       (((2 * ks + hi) ^ l7) << 3));
          oacc[nd] = __builtin_amdgcn_mfma_f32_32x32x16_bf16(pu.v, vf, oacc[nd], 0, 0, 0);
        }
      }
      __builtin_amdgcn_s_setprio(0);
    }

    if (havenext) {
      const int nb = cur ^ 1;
      u16x8 w0, w1;
      #pragma unroll
      for (int j = 0; j < 4; ++j) {
        w0[j] = f2b(kq[0][j]); w0[4 + j] = f2b(kq[1][j]);
        w1[j] = f2b(kq[2][j]); w1[4 + j] = f2b(kq[3][j]);
      }
      *(u16x8*)(&sm.kv.Kt[hs][nb][kwo0]) = w0;
      *(u16x8*)(&sm.kv.Kt[hs][nb][kwo1]) = w1;
      #pragma unroll
      for (int jd = 0; jd < 4; ++jd) {
        const int row = vd + jd;
        u16x4 vw;
        #pragma unroll
        for (int i = 0; i < 4; ++i) vw[i] = f2b(vq[i][jd]);
        *(u16x4*)(&sm.kv.Vt[hs][nb][row * 64 + (((vkv >> 3) ^ (row & 7)) << 3) + (vkv & 7)]) = vw;
      }
      __syncthreads();
      cur = nb;
    }
  }

  // ---- merge the two kv-halves (LDS aliases K/V buffers; barriered) ----
  __syncthreads();                  // all compute LDS reads done
  if (half == 1) {                  // publish unnormalized state
    #pragma unroll
    for (int r = 0; r < 16; ++r) {
      const int qrow = (r & 3) + 8 * (r >> 2) + 4 * hi;
      sm.cmb.O[32 * wv + qrow][l31]      = oacc[0][r];
      sm.cmb.O[32 * wv + qrow][32 + l31] = oacc[1][r];
    }
    if (hi == 0) { sm.cmb.m[32 * wv + l31] = m_run; sm.cmb.l[32 * wv + l31] = l_run; }
  }
  __syncthreads();
  if (half == 0) {                  // merge + normalize + store
    const float m_b = sm.cmb.m[32 * wv + l31];
    const float l_b = sm.cmb.l[32 * wv + l31];
    const float mm = fmaxf(m_run, m_b);
    const float sa = exp2f(m_run - mm);
    const float sb = exp2f(m_b - mm);          // m_b=-inf (empty half) -> 0
    const float linv = 1.0f / (sa * l_run + sb * l_b);
    const float wa = sa * linv, wb = sb * linv;
    float* Ob = O + (((size_t)b * L_ + q0w) * H_ + h) * E_;
    #pragma unroll
    for (int r = 0; r < 16; ++r) {
      const int qrow = (r & 3) + 8 * (r >> 2) + 4 * hi;
      const float wa_r = __shfl(wa, qrow);
      const float wb_r = __shfl(wb, qrow);
      Ob[(size_t)qrow * HE + l31] =
          wa_r * oacc[0][r] + wb_r * sm.cmb.O[32 * wv + qrow][l31];
      Ob[(size_t)qrow * HE + 32 + l31] =
          wa_r * oacc[1][r] + wb_r * sm.cmb.O[32 * wv + qrow][32 + l31];
    }
  }
}

extern "C" void kernel_launch(void* const* d_in, const int* in_sizes, int n_in,
                              void* d_out, int out_size, void* d_ws, size_t ws_size,
                              hipStream_t stream) {
  (void)in_sizes; (void)n_in; (void)out_size; (void)d_ws; (void)ws_size;
  const float* Q   = (const float*)d_in[0];
  const float* K   = (const float*)d_in[1];
  const float* V   = (const float*)d_in[2];
  // d_in[3] = attn_mask: ignored, causality applied analytically.
  const float* tau = (const float*)d_in[4];
  float* O = (float*)d_out;
  dim3 grid(L_ / 128, H_, B_), block(512);
  hipLaunchKernelGGL(attn_fwd, grid, block, 0, stream, Q, K, V, tau, O);
}